// Round 1
// baseline (100.424 us; speedup 1.0000x reference)
//
#include <hip/hip_runtime.h>

// Problem: TemporalAttention_54322746359850
// Identity: softmax rows sum to 1 and einsum('TNS,BNH->BNH') contracts attn over
// BOTH T and S => y == 1024*v exactly; adjacency/QK/softmax are dead code.
//   att    = (1024*(h_pred@Wv + bv)) @ Wo + bo
//   gate   = sigmoid( silu([h_pred,h_prev]@gW1 + gb1) @ gW2 + gb2 )
//   h_corr = h_prev + gate*att
//   out    = h_corr + relu([h_corr,h_prev]@mW1 + mb1) @ mW2 + mb2
// Inputs f32, output f32.
//
// R11 theory: rocprof top-5 shows per-iteration 256 MiB fillBufferAligned
// dispatches (~40 us each) = harness d_ws poison; our kernels are absent from
// the top-5 (each < 39.8 us) yet dur_us = 99.4 -> the timed graph contains
// ~80 us of ws-poison + ~19 us of our work. Experiment: go ws-FREE.
//   - no converter kernel, no d_ws use at all (single dispatch)
//   - f32 weights loaded directly; ROWS 4->8 (grid 256->128 blocks) keeps
//     total weight-broadcast bytes at R10 parity (512KB/block x 128 = 67 MB)
// If the ws poison is tied to ws use -> dur_us ~20 us. If unconditional ->
// ~93-100 us and we've still removed a dispatch + gap and have one clean
// kernel to profile.

#define HH 128
#define NROWS 1024
#define ROWS 8       // rows per block (was 4)
#define NT 512       // threads per block (8 waves)
#define NG 16        // c-groups (8 K-rows each per 128-K)

__device__ __forceinline__ void fma4(float4& a, float s, const float4& w) {
    a.x += s * w.x; a.y += s * w.y; a.z += s * w.z; a.w += s * w.w;
}

__global__ __launch_bounds__(NT) void temporal_attn_fused(
    const float* __restrict__ h_prev,
    const float* __restrict__ h_pred,
    const float* __restrict__ Wv,  const float* __restrict__ bv,
    const float* __restrict__ Wo,  const float* __restrict__ bo,
    const float* __restrict__ gW1, const float* __restrict__ gb1,
    const float* __restrict__ gW2, const float* __restrict__ gb2,
    const float* __restrict__ mW1, const float* __restrict__ mb1,
    const float* __restrict__ mW2, const float* __restrict__ mb2,
    float* __restrict__ out)
{
    __shared__ __align__(16) float sPred[ROWS][HH];
    __shared__ __align__(16) float sPrev[ROWS][HH];
    __shared__ __align__(16) float sBuf[ROWS][HH];   // a, then g1, then m1
    __shared__ __align__(16) float sCorr[ROWS][HH];
    __shared__ __align__(16) float sAtt[ROWS][HH];
    __shared__ float4 part4[NG][ROWS][HH / 4];       // 64 KB partials

    const int tid = threadIdx.x;
    const int jq  = tid & 31;                        // col-quad: cols 4*jq..4*jq+3
    const int cg  = ((tid >> 5) + blockIdx.x) & 15;  // rotated c-group: K-rows 8cg..8cg+7
    const int rr  = tid >> 7;                        // epilogue row 0..3 (also handles rr+4)
    const int jj  = tid & (HH - 1);                  // epilogue col 0..127
    const int r0  = blockIdx.x * ROWS;

    // ---- stage activations (coalesced, 2 rows/thread) + bias prefetch ----
    sPred[rr][jj]     = h_pred[(r0 + rr) * HH + jj];
    sPred[rr + 4][jj] = h_pred[(r0 + rr + 4) * HH + jj];
    sPrev[rr][jj]     = h_prev[(r0 + rr) * HH + jj];
    sPrev[rr + 4][jj] = h_prev[(r0 + rr + 4) * HH + jj];
    const float rbv  = bv[jj],  rbo  = bo[jj];
    const float rgb1 = gb1[jj], rgb2 = gb2[jj];
    const float rmb1 = mb1[jj], rmb2 = mb2[jj];
    __syncthreads();

    const float* pf = (const float*)part4;
    const int cb0 = rr * HH + jj;                    // combine read base, row rr
    const int cb1 = (rr + 4) * HH + jj;              // combine read base, row rr+4

    float4 wa[16], wb[8];
    float4 acc[ROWS];

    // load 8 float4 = K-rows 8cg..8cg+7 (+rp row offset), cols 4jq..4jq+3
    #define LWF(dst, off, W, rp) { \
        const float4* B4 = (const float4*)(W); \
        _Pragma("unroll") for (int i = 0; i < 8; ++i) \
            dst[(off) + i] = B4[((rp) + 8 * cg + i) * 32 + jq]; }

    #define ZACC() { _Pragma("unroll") for (int r = 0; r < ROWS; ++r) \
        acc[r] = make_float4(0.f, 0.f, 0.f, 0.f); }

    // acc[r] += sum_i S[r][8cg+i] * W[8cg+i][4jq..] , i = 0..7
    #define FMAB(S, wp, woff) { \
        _Pragma("unroll") for (int r = 0; r < ROWS; ++r) { \
            const float4 s0 = *(const float4*)&S[r][8 * cg]; \
            const float4 s1 = *(const float4*)&S[r][8 * cg + 4]; \
            fma4(acc[r], s0.x, wp[(woff) + 0]); \
            fma4(acc[r], s0.y, wp[(woff) + 1]); \
            fma4(acc[r], s0.z, wp[(woff) + 2]); \
            fma4(acc[r], s0.w, wp[(woff) + 3]); \
            fma4(acc[r], s1.x, wp[(woff) + 4]); \
            fma4(acc[r], s1.y, wp[(woff) + 5]); \
            fma4(acc[r], s1.z, wp[(woff) + 6]); \
            fma4(acc[r], s1.w, wp[(woff) + 7]); } }

    #define PSTORE() { \
        _Pragma("unroll") for (int r = 0; r < ROWS; ++r) part4[cg][r][jq] = acc[r]; \
        __syncthreads(); }

    // combine 16 partials for the thread's two output elements
    #define COMBINE2(d0, d1) \
        float d0 = 0.f, d1 = 0.f; \
        _Pragma("unroll") for (int g = 0; g < NG; ++g) { \
            d0 += pf[g * (ROWS * HH) + cb0]; \
            d1 += pf[g * (ROWS * HH) + cb1]; }

    // ---- step 1: a = 1024*(h_pred @ Wv + bv) -> sBuf ----
    LWF(wa, 0, Wv, 0);           // s1 weights
    LWF(wb, 0, Wo, 0);           // prefetch s2
    ZACC(); FMAB(sPred, wa, 0);
    LWF(wa, 0, gW1, 0);          // prefetch s3 (both halves of K=256)
    LWF(wa, 8, gW1, 128);
    PSTORE();
    { COMBINE2(d0, d1);
      sBuf[rr][jj]     = 1024.f * (d0 + rbv);
      sBuf[rr + 4][jj] = 1024.f * (d1 + rbv); }
    __syncthreads();

    // ---- step 2: att = a @ Wo + bo -> sAtt ----
    ZACC(); FMAB(sBuf, wb, 0);
    LWF(wb, 0, gW2, 0);          // prefetch s4
    PSTORE();
    { COMBINE2(d0, d1);
      sAtt[rr][jj]     = d0 + rbo;
      sAtt[rr + 4][jj] = d1 + rbo; }
    __syncthreads();

    // ---- step 3: g1 = silu([h_pred,h_prev] @ gW1 + gb1) -> sBuf ----
    ZACC(); FMAB(sPred, wa, 0); FMAB(sPrev, wa, 8);
    LWF(wa, 0, mW1, 0);          // prefetch s5 (both halves)
    LWF(wa, 8, mW1, 128);
    PSTORE();
    { COMBINE2(d0, d1);
      float x0 = d0 + rgb1, x1 = d1 + rgb1;
      sBuf[rr][jj]     = x0 / (1.f + __expf(-x0));
      sBuf[rr + 4][jj] = x1 / (1.f + __expf(-x1)); }
    __syncthreads();

    // ---- step 4: gate = sigmoid(g1 @ gW2 + gb2); h_corr = h_prev + gate*att ----
    ZACC(); FMAB(sBuf, wb, 0);
    LWF(wb, 0, mW2, 0);          // prefetch s6
    PSTORE();
    { COMBINE2(d0, d1);
      float g0 = 1.f / (1.f + __expf(-(d0 + rgb2)));
      float g1 = 1.f / (1.f + __expf(-(d1 + rgb2)));
      sCorr[rr][jj]     = sPrev[rr][jj]     + g0 * sAtt[rr][jj];
      sCorr[rr + 4][jj] = sPrev[rr + 4][jj] + g1 * sAtt[rr + 4][jj]; }
    __syncthreads();

    // ---- step 5: m1 = relu([h_corr,h_prev] @ mW1 + mb1) -> sBuf ----
    ZACC(); FMAB(sCorr, wa, 0); FMAB(sPrev, wa, 8);
    PSTORE();
    { COMBINE2(d0, d1);
      sBuf[rr][jj]     = fmaxf(d0 + rmb1, 0.f);
      sBuf[rr + 4][jj] = fmaxf(d1 + rmb1, 0.f); }
    __syncthreads();

    // ---- step 6: out = h_corr + m1 @ mW2 + mb2 ----
    ZACC(); FMAB(sBuf, wb, 0);
    PSTORE();
    { COMBINE2(d0, d1);
      out[(r0 + rr) * HH + jj]     = sCorr[rr][jj]     + d0 + rmb2;
      out[(r0 + rr + 4) * HH + jj] = sCorr[rr + 4][jj] + d1 + rmb2; }
}

extern "C" void kernel_launch(void* const* d_in, const int* in_sizes, int n_in,
                              void* d_out, int out_size, void* d_ws, size_t ws_size,
                              hipStream_t stream) {
    // setup_inputs order:
    // 0 h_prev, 1 h_pred, 2 adj_rows, 3 adj_cols,
    // 4 Wq, 5 bq, 6 Wk, 7 bk, 8 Wv, 9 bv, 10 Wo, 11 bo,
    // 12 gW1, 13 gb1, 14 gW2, 15 gb2, 16 mW1, 17 mb1, 18 mW2, 19 mb2
    const float* h_prev = (const float*)d_in[0];
    const float* h_pred = (const float*)d_in[1];
    const float* Wv  = (const float*)d_in[8];
    const float* bv  = (const float*)d_in[9];
    const float* Wo  = (const float*)d_in[10];
    const float* bo  = (const float*)d_in[11];
    const float* gW1 = (const float*)d_in[12];
    const float* gb1 = (const float*)d_in[13];
    const float* gW2 = (const float*)d_in[14];
    const float* gb2 = (const float*)d_in[15];
    const float* mW1 = (const float*)d_in[16];
    const float* mb1 = (const float*)d_in[17];
    const float* mW2 = (const float*)d_in[18];
    const float* mb2 = (const float*)d_in[19];
    float* out = (float*)d_out;
    (void)d_ws; (void)ws_size;   // deliberately unused: R11 ws-free experiment

    hipLaunchKernelGGL(temporal_attn_fused, dim3(NROWS / ROWS), dim3(NT), 0, stream,
                       h_prev, h_pred, Wv, bv, Wo, bo, gW1, gb1, gW2, gb2,
                       mW1, mb1, mW2, mb2, out);
}

// Round 3
// 100.001 us; speedup vs baseline: 1.0042x; 1.0042x over previous
//
#include <hip/hip_runtime.h>

// Problem: TemporalAttention_54322746359850
// Identity: softmax rows sum to 1 and einsum('TNS,BNH->BNH') contracts attn over
// BOTH T and S => y == 1024*v exactly; adjacency/QK/softmax are dead code.
//   att    = (1024*(h_pred@Wv + bv)) @ Wo + bo
//   gate   = sigmoid( silu([h_pred,h_prev]@gW1 + gb1) @ gW2 + gb2 )
//   h_corr = h_prev + gate*att
//   out    = h_corr + relu([h_corr,h_prev]@mW1 + mb1) @ mW2 + mb2
// Inputs f32, output f32.
//
// R12: R11 proved the 2x256MiB ws-poison fills (~80us @ 84% HBM peak) are
// UNCONDITIONAL -> d_ws use is free; our controllable slice is ~20us.
// Revert to R10's proven bf16-ws broadcast (67MB) + ROWS=4/grid=256 (all CUs),
// and collapse the 6-round chain to 4 rounds via the dataflow DAG:
//   R1: s1||s3  (both read only sPred/sPrev)
//   R2: s2||s4  (independent given sA,sG1; corr computed in-thread, sAtt gone)
//   R3: s5   R4: s6
// -4 barriers, -2 serial partial-combine round trips, 2x FMA ILP per pass.
// Math order identical to R10 -> absmax should return to 16.0.
// (R12b: rename COMBINE1(do) -> dfin; `do` is a keyword.)

#define HH 128
#define NROWS 1024
#define ROWS 4      // rows per block
#define NT 512      // threads per block (8 waves)
#define NG 16       // c-groups (8 K-rows each per 128-K)

// d_ws layout (uint32 units): packed bf16 row-pairs, elem[k2*128+j] = W[2k2][j] | W[2k2+1][j]<<16
#define WS_WV  0
#define WS_WO  8192
#define WS_GW1 16384
#define WS_GW2 32768
#define WS_MW1 40960
#define WS_MW2 57344

__device__ __forceinline__ unsigned int f2bf16(float f) {
    union { float f; unsigned int i; } x; x.f = f;
    unsigned int lsb = (x.i >> 16) & 1u;
    return (x.i + 0x7FFFu + lsb) >> 16;   // RNE
}

__global__ __launch_bounds__(256) void convert_weights(
    const float* __restrict__ Wv,  const float* __restrict__ Wo,
    const float* __restrict__ gW1, const float* __restrict__ gW2,
    const float* __restrict__ mW1, const float* __restrict__ mW2,
    unsigned int* __restrict__ dst)
{
    const int b = blockIdx.x;
    const float* src; unsigned int* d; int lb;
    if      (b < 32)  { src = Wv;  d = dst + WS_WV;  lb = b; }
    else if (b < 64)  { src = Wo;  d = dst + WS_WO;  lb = b - 32; }
    else if (b < 128) { src = gW1; d = dst + WS_GW1; lb = b - 64; }
    else if (b < 160) { src = gW2; d = dst + WS_GW2; lb = b - 128; }
    else if (b < 224) { src = mW1; d = dst + WS_MW1; lb = b - 160; }
    else              { src = mW2; d = dst + WS_MW2; lb = b - 224; }
    const int e  = lb * 256 + threadIdx.x;   // = k2*128 + j
    const int k2 = e >> 7, j = e & 127;
    const unsigned int lo = f2bf16(src[(2 * k2) * HH + j]);
    const unsigned int hi = f2bf16(src[(2 * k2 + 1) * HH + j]);
    d[e] = lo | (hi << 16);
}

__device__ __forceinline__ void fma4(float4& a, float s, const float4& w) {
    a.x += s * w.x; a.y += s * w.y; a.z += s * w.z; a.w += s * w.w;
}
__device__ __forceinline__ float4 bflo4(uint4 q) {
    return make_float4(__uint_as_float(q.x << 16), __uint_as_float(q.y << 16),
                       __uint_as_float(q.z << 16), __uint_as_float(q.w << 16));
}
__device__ __forceinline__ float4 bfhi4(uint4 q) {
    return make_float4(__uint_as_float(q.x & 0xffff0000u), __uint_as_float(q.y & 0xffff0000u),
                       __uint_as_float(q.z & 0xffff0000u), __uint_as_float(q.w & 0xffff0000u));
}

__global__ __launch_bounds__(NT) void temporal_attn_fused(
    const float* __restrict__ h_prev,
    const float* __restrict__ h_pred,
    const unsigned int* __restrict__ wbf,   // packed bf16 weights in d_ws
    const float* __restrict__ bv,  const float* __restrict__ bo,
    const float* __restrict__ gb1, const float* __restrict__ gb2,
    const float* __restrict__ mb1, const float* __restrict__ mb2,
    float* __restrict__ out)
{
    __shared__ __align__(16) float sPred[ROWS][HH];
    __shared__ __align__(16) float sPrev[ROWS][HH];
    __shared__ __align__(16) float sA[ROWS][HH];     // a (scaled), round 1 out
    __shared__ __align__(16) float sG1[ROWS][HH];    // g1, then m1 (round 3 out)
    __shared__ __align__(16) float sCorr[ROWS][HH];  // h_corr (round 2 out)
    __shared__ float4 part4[NG][2][ROWS][HH / 4];    // 64 KB partials (2 outputs/round)

    const int tid = threadIdx.x;
    const int jq  = tid & 31;                        // col-quad: cols 4*jq..4*jq+3
    const int cg  = ((tid >> 5) + blockIdx.x) & 15;  // rotated c-group: K-rows 8cg..8cg+7
    const int rr  = tid >> 7;                        // epilogue row 0..3
    const int jj  = tid & (HH - 1);                  // epilogue col 0..127
    const int r0  = blockIdx.x * ROWS;

    // ---- stage activations (coalesced) + bias prefetch ----
    sPred[rr][jj] = h_pred[(r0 + rr) * HH + jj];
    sPrev[rr][jj] = h_prev[(r0 + rr) * HH + jj];
    const float rbv  = bv[jj],  rbo  = bo[jj];
    const float rgb1 = gb1[jj], rgb2 = gb2[jj];
    const float rmb1 = mb1[jj], rmb2 = mb2[jj];
    __syncthreads();

    const float* pf = (const float*)part4;
    const int cbase = rr * HH + jj;                  // combine read base (dwords)

    uint4 wa[12], wb[8];
    float4 acc[8];

    // load 4 uint4 = K-row-pairs 4cg..4cg+3 (+rp offset), cols 4jq..4jq+3
    #define LWB(dst, off, wsoff, rp) { \
        const uint4* B4 = (const uint4*)(wbf + (wsoff)); \
        _Pragma("unroll") for (int i = 0; i < 4; ++i) \
            dst[(off) + i] = B4[((rp) + 4 * cg + i) * 32 + jq]; }

    #define ZACC(n) { _Pragma("unroll") for (int r = 0; r < (n); ++r) \
        acc[r] = make_float4(0.f, 0.f, 0.f, 0.f); }

    // acc[aoff+r] += S[r][8cg+2i]*lo + S[r][8cg+2i+1]*hi over i=0..3
    #define FMAB(S, wp, woff, aoff) { \
        _Pragma("unroll") for (int i = 0; i < 4; ++i) { \
            float4 wl = bflo4(wp[(woff) + i]); \
            float4 wh = bfhi4(wp[(woff) + i]); \
            _Pragma("unroll") for (int r = 0; r < ROWS; ++r) { \
                fma4(acc[(aoff) + r], S[r][8 * cg + 2 * i],     wl); \
                fma4(acc[(aoff) + r], S[r][8 * cg + 2 * i + 1], wh); } } }

    #define PSTORE2() { \
        _Pragma("unroll") for (int r = 0; r < ROWS; ++r) { \
            part4[cg][0][r][jq] = acc[r]; \
            part4[cg][1][r][jq] = acc[4 + r]; } \
        __syncthreads(); }

    #define PSTORE1() { \
        _Pragma("unroll") for (int r = 0; r < ROWS; ++r) part4[cg][0][r][jq] = acc[r]; \
        __syncthreads(); }

    #define COMBINE2(d0, d1) \
        float d0 = 0.f, d1 = 0.f; \
        _Pragma("unroll") for (int g = 0; g < NG; ++g) { \
            d0 += pf[g * (2 * ROWS * HH) + cbase]; \
            d1 += pf[g * (2 * ROWS * HH) + (ROWS * HH) + cbase]; }

    #define COMBINE1(d0) \
        float d0 = 0.f; \
        _Pragma("unroll") for (int g = 0; g < NG; ++g) \
            d0 += pf[g * (2 * ROWS * HH) + cbase];

    // ---- round 1: a = 1024*(h_pred@Wv + bv)  ||  g1 = silu([h_pred,h_prev]@gW1 + gb1) ----
    LWB(wa, 0, WS_WV,  0);       // Wv
    LWB(wa, 4, WS_GW1, 0);       // gW1 rows 0..127  (x h_pred)
    LWB(wa, 8, WS_GW1, 64);      // gW1 rows 128..255 (x h_prev)
    ZACC(8);
    FMAB(sPred, wa, 0, 0);       // -> a partial
    FMAB(sPred, wa, 4, 4);       // -> g1 partial (first half)
    FMAB(sPrev, wa, 8, 4);       // -> g1 partial (second half)
    LWB(wb, 0, WS_WO,  0);       // prefetch round 2
    LWB(wb, 4, WS_GW2, 0);
    PSTORE2();
    { COMBINE2(da, dg);
      sA[rr][jj] = 1024.f * (da + rbv);
      float x = dg + rgb1;
      sG1[rr][jj] = x / (1.f + __expf(-x)); }
    __syncthreads();

    // ---- round 2: att = sA@Wo + bo  ||  glogit = sG1@gW2 + gb2 ; corr in-thread ----
    ZACC(8);
    FMAB(sA,  wb, 0, 0);         // -> att partial
    FMAB(sG1, wb, 4, 4);         // -> gate-logit partial
    LWB(wa, 0, WS_MW1, 0);       // prefetch round 3 (both halves of K=256)
    LWB(wa, 4, WS_MW1, 64);
    PSTORE2();
    { COMBINE2(datt, dgl);
      float att  = datt + rbo;
      float gate = 1.f / (1.f + __expf(-(dgl + rgb2)));
      sCorr[rr][jj] = sPrev[rr][jj] + gate * att; }
    __syncthreads();

    // ---- round 3: m1 = relu([h_corr,h_prev]@mW1 + mb1) -> sG1 (reused) ----
    ZACC(4);
    FMAB(sCorr, wa, 0, 0);
    FMAB(sPrev, wa, 4, 0);
    LWB(wb, 0, WS_MW2, 0);       // prefetch round 4
    PSTORE1();
    { COMBINE1(dm);
      sG1[rr][jj] = fmaxf(dm + rmb1, 0.f); }
    __syncthreads();

    // ---- round 4: out = h_corr + m1@mW2 + mb2 ----
    ZACC(4);
    FMAB(sG1, wb, 0, 0);
    PSTORE1();
    { COMBINE1(dfin);
      out[(r0 + rr) * HH + jj] = sCorr[rr][jj] + dfin + rmb2; }
}

extern "C" void kernel_launch(void* const* d_in, const int* in_sizes, int n_in,
                              void* d_out, int out_size, void* d_ws, size_t ws_size,
                              hipStream_t stream) {
    // setup_inputs order:
    // 0 h_prev, 1 h_pred, 2 adj_rows, 3 adj_cols,
    // 4 Wq, 5 bq, 6 Wk, 7 bk, 8 Wv, 9 bv, 10 Wo, 11 bo,
    // 12 gW1, 13 gb1, 14 gW2, 15 gb2, 16 mW1, 17 mb1, 18 mW2, 19 mb2
    const float* h_prev = (const float*)d_in[0];
    const float* h_pred = (const float*)d_in[1];
    const float* Wv  = (const float*)d_in[8];
    const float* bv  = (const float*)d_in[9];
    const float* Wo  = (const float*)d_in[10];
    const float* bo  = (const float*)d_in[11];
    const float* gW1 = (const float*)d_in[12];
    const float* gb1 = (const float*)d_in[13];
    const float* gW2 = (const float*)d_in[14];
    const float* gb2 = (const float*)d_in[15];
    const float* mW1 = (const float*)d_in[16];
    const float* mb1 = (const float*)d_in[17];
    const float* mW2 = (const float*)d_in[18];
    const float* mb2 = (const float*)d_in[19];
    float* out = (float*)d_out;
    unsigned int* wbf = (unsigned int*)d_ws;

    hipLaunchKernelGGL(convert_weights, dim3(256), dim3(256), 0, stream,
                       Wv, Wo, gW1, gW2, mW1, mW2, wbf);

    hipLaunchKernelGGL(temporal_attn_fused, dim3(NROWS / ROWS), dim3(NT), 0, stream,
                       h_prev, h_pred, wbf, bv, bo, gb1, gb2, mb1, mb2, out);
}